// Round 3
// baseline (310.041 us; speedup 1.0000x reference)
//
#include <hip/hip_runtime.h>
#include <hip/hip_bf16.h>

// Problem constants (ClusterMemory forward, mode='CM')
#define NSAMP   65536
#define NFEAT   256
#define BATCHSZ 512
#define LOGITS_ELEMS ((size_t)BATCHSZ * NSAMP)

typedef __attribute__((ext_vector_type(4))) float f32x4;
typedef __attribute__((ext_vector_type(8))) short bf16x8;

// GEMM tiling
#define BM 128
#define BN 128
#define BK 64

__device__ inline unsigned short bf16_bits(float x) {
  return __builtin_bit_cast(unsigned short, __float2bfloat16(x));
}

// ---------------------------------------------------------------------------
// logits = (inputs @ features^T) * (1/0.05), via split-bf16 3-term MFMA.
// Blocks with m_tile==0 additionally copy the features tile (already loaded
// for staging) into the new_features output region (saves a 64MB re-read).
// ---------------------------------------------------------------------------
__global__ __launch_bounds__(256, 2)
void cm_gemm_kernel(const float* __restrict__ inputs,
                    const float* __restrict__ features,
                    float* __restrict__ logits,
                    float* __restrict__ newF) {
  // LDS: Ahi | Alo | Bhi | Blo, each BM*BK bf16 = 16 KB -> 64 KB total
  __shared__ __align__(16) char smem[4 * BM * BK * 2];

  const int tid    = threadIdx.x;
  const int bidx   = blockIdx.x;
  const int m_tile = bidx & 3;          // m inner: the 4 sharers of a B-panel
  const int n_tile = bidx >> 2;         // are temporally adjacent (L2/L3 hot)
  const int bm0    = m_tile * BM;
  const int bn0    = n_tile * BN;

  const int wave  = tid >> 6;
  const int lane  = tid & 63;
  const int m_off = (wave >> 1) * 64;
  const int n_off = (wave & 1) * 64;

  f32x4 acc[4][4];
  #pragma unroll
  for (int m = 0; m < 4; ++m)
    #pragma unroll
    for (int n = 0; n < 4; ++n) {
      acc[m][n][0] = 0.0f; acc[m][n][1] = 0.0f;
      acc[m][n][2] = 0.0f; acc[m][n][3] = 0.0f;
    }

  const int srow = tid >> 3;  // 0..31 (base row of sweep)
  const int slot = tid & 7;   // 16B slot within row (8 floats)

  for (int ks = 0; ks < 4; ++ks) {
    const int k0 = ks * BK;
    if (ks) __syncthreads();

    // ---- stage A and B (fp32 -> bf16 hi/lo) into XOR-swizzled LDS ----
    #pragma unroll
    for (int s = 0; s < 4; ++s) {
      const int row     = srow + s * 32;
      const int byteoff = row * 128 + ((slot * 16) ^ ((row & 7) << 4));

      {  // A tile (inputs)
        const float* g = inputs + (size_t)(bm0 + row) * NFEAT + k0 + slot * 8;
        f32x4 v0 = *(const f32x4*)g;
        f32x4 v1 = *(const f32x4*)(g + 4);
        bf16x8 hi, lo;
        #pragma unroll
        for (int e = 0; e < 8; ++e) {
          float x = (e < 4) ? v0[e & 3] : v1[e & 3];
          unsigned short h = bf16_bits(x);
          float hf = __bfloat162float(__builtin_bit_cast(__hip_bfloat16, h));
          hi[e] = (short)h;
          lo[e] = (short)bf16_bits(x - hf);
        }
        *(bf16x8*)(smem + byteoff)         = hi;
        *(bf16x8*)(smem + 16384 + byteoff) = lo;
      }
      {  // B tile (features)
        const float* g = features + (size_t)(bn0 + row) * NFEAT + k0 + slot * 8;
        f32x4 v0 = *(const f32x4*)g;
        f32x4 v1 = *(const f32x4*)(g + 4);
        bf16x8 hi, lo;
        #pragma unroll
        for (int e = 0; e < 8; ++e) {
          float x = (e < 4) ? v0[e & 3] : v1[e & 3];
          unsigned short h = bf16_bits(x);
          float hf = __bfloat162float(__builtin_bit_cast(__hip_bfloat16, h));
          hi[e] = (short)h;
          lo[e] = (short)bf16_bits(x - hf);
        }
        *(bf16x8*)(smem + 32768 + byteoff) = hi;
        *(bf16x8*)(smem + 49152 + byteoff) = lo;
        if (m_tile == 0) {  // fused features -> new_features copy
          float* o = newF + (size_t)(bn0 + row) * NFEAT + k0 + slot * 8;
          *(f32x4*)o       = v0;
          *(f32x4*)(o + 4) = v1;
        }
      }
    }
    __syncthreads();

    // ---- MFMA inner loop: 2 chunks of K=32, 3-term split product ----
    #pragma unroll
    for (int kc = 0; kc < 2; ++kc) {
      const int kbyte = kc * 64 + ((lane >> 4) << 4);
      const int xr    = (lane & 7) << 4;  // == (row&7)<<4 for all frag rows
      bf16x8 ah[4], al[4], bh[4], bl[4];
      #pragma unroll
      for (int m = 0; m < 4; ++m) {
        const int r   = m_off + m * 16 + (lane & 15);
        const int off = r * 128 + (kbyte ^ xr);
        ah[m] = *(const bf16x8*)(smem + off);
        al[m] = *(const bf16x8*)(smem + 16384 + off);
      }
      #pragma unroll
      for (int n = 0; n < 4; ++n) {
        const int r   = n_off + n * 16 + (lane & 15);
        const int off = r * 128 + (kbyte ^ xr);
        bh[n] = *(const bf16x8*)(smem + 32768 + off);
        bl[n] = *(const bf16x8*)(smem + 49152 + off);
      }
      #pragma unroll
      for (int m = 0; m < 4; ++m)
        #pragma unroll
        for (int n = 0; n < 4; ++n) {
          acc[m][n] = __builtin_amdgcn_mfma_f32_16x16x32_bf16(ah[m], bh[n], acc[m][n], 0, 0, 0);
          acc[m][n] = __builtin_amdgcn_mfma_f32_16x16x32_bf16(al[m], bh[n], acc[m][n], 0, 0, 0);
          acc[m][n] = __builtin_amdgcn_mfma_f32_16x16x32_bf16(ah[m], bl[n], acc[m][n], 0, 0, 0);
        }
    }
  }

  // ---- epilogue: C/D mapping col=lane&15, row=(lane>>4)*4+reg [m89] ----
  const float scale = 1.0f / 0.05f;  // folded; matches reference's /0.05f
  const int c_col      = bn0 + n_off + (lane & 15);
  const int c_row_base = bm0 + m_off + ((lane >> 4) << 2);
  #pragma unroll
  for (int m = 0; m < 4; ++m) {
    #pragma unroll
    for (int n = 0; n < 4; ++n) {
      f32x4 v = acc[m][n];
      size_t base = (size_t)(c_row_base + m * 16) * NSAMP + (size_t)(c_col + n * 16);
      logits[base]             = v[0] * scale;
      logits[base + NSAMP]     = v[1] * scale;
      logits[base + 2 * NSAMP] = v[2] * scale;
      logits[base + 3 * NSAMP] = v[3] * scale;
    }
  }
}

// ---------------------------------------------------------------------------
// Order-dependent EMA scatter: one wave per batch index. Only the LAST batch
// index targeting a given row writes; it replays the full ordered chain.
// ---------------------------------------------------------------------------
__global__ __launch_bounds__(64)
void cm_update_kernel(const float* __restrict__ inputs,
                      const int* __restrict__ targets,
                      const float* __restrict__ features,
                      float* __restrict__ newF) {
  const int i    = blockIdx.x;
  const int lane = threadIdx.x;
  const int y    = targets[i];

  // 512-bit mask of batch indices targeting y (8 x 64-lane ballots)
  unsigned long long m[8];
  #pragma unroll
  for (int c = 0; c < 8; ++c)
    m[c] = __ballot(targets[c * 64 + lane] == y);

  int maxj = -1;
  #pragma unroll
  for (int c = 7; c >= 0; --c)
    if (maxj < 0 && m[c]) maxj = c * 64 + 63 - __clzll(m[c]);
  if (maxj != i) return;  // not the last writer for y

  f32x4 row = *(const f32x4*)(features + (size_t)y * NFEAT + lane * 4);
  for (int c = 0; c < 8; ++c) {
    unsigned long long mm = m[c];
    while (mm) {  // wave-uniform loop (ballot masks are uniform)
      const int b = __builtin_ctzll(mm);
      mm &= mm - 1;
      const int j = c * 64 + b;
      f32x4 x = *(const f32x4*)(inputs + (size_t)j * NFEAT + lane * 4);
      row[0] = 0.2f * row[0] + 0.8f * x[0];
      row[1] = 0.2f * row[1] + 0.8f * x[1];
      row[2] = 0.2f * row[2] + 0.8f * x[2];
      row[3] = 0.2f * row[3] + 0.8f * x[3];
      float p = row[0]*row[0] + row[1]*row[1] + row[2]*row[2] + row[3]*row[3];
      #pragma unroll
      for (int off = 32; off >= 1; off >>= 1)
        p += __shfl_xor(p, off);
      const float inv = 1.0f / sqrtf(p + 1e-12f);
      row[0] *= inv; row[1] *= inv; row[2] *= inv; row[3] *= inv;
    }
  }
  *(f32x4*)(newF + (size_t)y * NFEAT + lane * 4) = row;
}

// ---------------------------------------------------------------------------
extern "C" void kernel_launch(void* const* d_in, const int* in_sizes, int n_in,
                              void* d_out, int out_size, void* d_ws, size_t ws_size,
                              hipStream_t stream) {
  const float* inputs   = (const float*)d_in[0];
  const int*   targets  = (const int*)d_in[1];
  const float* features = (const float*)d_in[2];
  float* logits = (float*)d_out;
  float* newF   = (float*)d_out + LOGITS_ELEMS;

  const int grid = (NSAMP / BN) * (BATCHSZ / BM);  // 512 * 4 = 2048
  cm_gemm_kernel<<<grid, 256, 0, stream>>>(inputs, features, logits, newF);
  cm_update_kernel<<<BATCHSZ, 64, 0, stream>>>(inputs, targets, features, newF);
}